// Round 1
// baseline (91.929 us; speedup 1.0000x reference)
//
#include <hip/hip_runtime.h>
#include <hip/hip_cooperative_groups.h>

namespace cg = cooperative_groups;

// x (16,16,64,64) f32, weight (16,64) f32, nodes (64,) f32 -> scalar f32.
constexpr int F_ = 16, N_ = 64;
constexpr int TOTAL = 16 * 16 * 64 * 64;         // 1,048,576 elements
constexpr int VEC = TOTAL / 4;                   // 262,144 float4
constexpr int THREADS = 1024;
constexpr int BLOCKS = VEC / THREADS;            // 256 blocks -> 1 float4/thread
constexpr float LOWER = -3.0f, UPPER = 3.0f;

// Closed-form 5-point quartic B-spline window (see prior rounds).
// Single cooperative kernel: per-block partial -> grid.sync -> block 0 reduces.
// 256 blocks x 1024 thr = 16 waves/CU on 256 CUs -> co-resident, grid.sync legal.
__global__ __launch_bounds__(THREADS) void spline_fused(
    const float* __restrict__ x,
    const float* __restrict__ weight,
    float* __restrict__ partials,
    float* __restrict__ out)
{
    __shared__ float ew[F_ * N_];            // exp(weight), 4 KiB
    __shared__ float wpart[THREADS / 64];
    const int tid = threadIdx.x;
    ew[tid] = __expf(weight[tid]);           // 1024 threads, 1024 weights
    __syncthreads();

    const int idx4 = blockIdx.x * THREADS + tid;
    const float4 v = reinterpret_cast<const float4*>(x)[idx4];
    // f = (elem>>12)&15 = (idx4>>10)&15 = blockIdx.x&15  (wave-uniform base)
    const float* __restrict__ ewf = &ew[(blockIdx.x & (F_ - 1)) * N_];

    const float vals[4] = {v.x, v.y, v.z, v.w};
    float local = 0.0f;

    #pragma unroll
    for (int j = 0; j < 4; ++j) {
        const float u = fmaf(vals[j], 10.5f, 31.5f);   // (x+3)*10.5
        const float r = rintf(u);
        const float s = u - r;                         // [-0.5, 0.5]
        const int n0 = (int)r - 2;

        const float p = 0.5f - s, q = 0.5f + s;
        const float p2 = p * p, q2 = q * q, s2 = s * s;
        float w[5];
        w[0] = p2 * p2;
        w[1] = 1.0f + p * (4.0f + p * (6.0f + p * (4.0f - 4.0f * p)));
        w[2] = fmaf(s2, fmaf(s2, 6.0f, -15.0f), 14.375f);
        w[3] = 1.0f + q * (4.0f + q * (6.0f + q * (4.0f - 4.0f * q)));
        w[4] = q2 * q2;

        float y = 0.0f;
        #pragma unroll
        for (int d = 0; d < 5; ++d) {
            const int n = n0 + d;
            const bool valid = ((unsigned)n < (unsigned)N_);
            const float wd = valid ? w[d] : 0.0f;
            y += wd * ewf[valid ? n : 0];
        }
        local += __logf(fmaf(y, 1.0f / 24.0f, 1e-7f));
    }

    // wave-64 butterfly, then LDS across the block's 16 waves.
    #pragma unroll
    for (int off = 32; off > 0; off >>= 1)
        local += __shfl_down(local, off, 64);

    if ((tid & 63) == 0) wpart[tid >> 6] = local;
    __syncthreads();
    if (tid == 0) {
        float s = 0.0f;
        #pragma unroll
        for (int i = 0; i < THREADS / 64; ++i) s += wpart[i];
        partials[blockIdx.x] = s;   // plain store; grid.sync provides release
    }

    // ---- grid-wide barrier, then block 0 reduces the 256 partials ----
    cg::this_grid().sync();

    if (blockIdx.x == 0) {
        float v2 = 0.0f;
        if (tid < BLOCKS) {
            v2 = partials[tid];     // 256 partials, threads 0..255 (4 waves)
            #pragma unroll
            for (int off = 32; off > 0; off >>= 1)
                v2 += __shfl_down(v2, off, 64);
            if ((tid & 63) == 0) wpart[tid >> 6] = v2;
        }
        __syncthreads();
        if (tid == 0) out[0] = wpart[0] + wpart[1] + wpart[2] + wpart[3];
    }
}

extern "C" void kernel_launch(void* const* d_in, const int* in_sizes, int n_in,
                              void* d_out, int out_size, void* d_ws, size_t ws_size,
                              hipStream_t stream) {
    const float* x      = (const float*)d_in[0];
    const float* weight = (const float*)d_in[1];
    float* out      = (float*)d_out;
    float* partials = (float*)d_ws;   // 256 floats of scratch

    void* args[] = {(void*)&x, (void*)&weight, (void*)&partials, (void*)&out};
    hipLaunchCooperativeKernel((const void*)spline_fused,
                               dim3(BLOCKS), dim3(THREADS), args, 0, stream);
}

// Round 2
// 60.295 us; speedup vs baseline: 1.5247x; 1.5247x over previous
//
#include <hip/hip_runtime.h>

// x (16,16,64,64) f32, weight (16,64) f32, nodes (64,) f32 -> scalar f32.
constexpr int F_ = 16, N_ = 64;
constexpr int TOTAL = 16 * 16 * 64 * 64;         // 1,048,576 elements
constexpr int VEC = TOTAL / 4;                   // 262,144 float4
constexpr int THREADS = 1024;
constexpr int BLOCKS = VEC / THREADS;            // 256 blocks -> 1 float4/thread
constexpr float LOWER = -3.0f, UPPER = 3.0f;

// Closed-form 5-point quartic B-spline window.
// u = (x - LOWER)*10.5 ; s = u - rint(u) in [-0.5, 0.5]; nodes rint(u)-2 .. +2.
// w0 = p^4, w1 = 1+4p+6p^2+4p^3-4p^4, w2 = 6s^4-15s^2+14.375,
// w3 = w1(q), w4 = q^4  (p = 0.5-s, q = 0.5+s), all /24.
//
// NOTE (R1 post-mortem): do NOT convert this to hipLaunchCooperativeKernel —
// coop launches are not graph-capturable; the harness's graph replay then pays
// ~30 µs/iteration of launch overhead (measured 59.9 -> 91.9 µs).
__global__ __launch_bounds__(THREADS) void spline_partial(
    const float* __restrict__ x,
    const float* __restrict__ weight,
    float* __restrict__ partials)
{
    __shared__ float ew[F_ * N_];   // exp(weight), 4 KiB
    const int tid = threadIdx.x;
    ew[tid] = __expf(weight[tid]);  // 1024 threads, 1024 weights
    __syncthreads();

    const int idx4 = blockIdx.x * THREADS + tid;
    const float4 v = reinterpret_cast<const float4*>(x)[idx4];
    // f = (elem>>12)&15 = (idx4>>10)&15 = blockIdx.x&15  (wave-uniform base)
    const float* __restrict__ ewf = &ew[(blockIdx.x & (F_ - 1)) * N_];

    const float vals[4] = {v.x, v.y, v.z, v.w};
    float local = 0.0f;

    #pragma unroll
    for (int j = 0; j < 4; ++j) {
        const float u = fmaf(vals[j], 10.5f, 31.5f);   // (x+3)*10.5
        const float r = rintf(u);
        const float s = u - r;                         // [-0.5, 0.5]
        const int n0 = (int)r - 2;

        const float p = 0.5f - s, q = 0.5f + s;
        const float p2 = p * p, q2 = q * q, s2 = s * s;
        float w[5];
        w[0] = p2 * p2;
        w[1] = 1.0f + p * (4.0f + p * (6.0f + p * (4.0f - 4.0f * p)));
        w[2] = fmaf(s2, fmaf(s2, 6.0f, -15.0f), 14.375f);
        w[3] = 1.0f + q * (4.0f + q * (6.0f + q * (4.0f - 4.0f * q)));
        w[4] = q2 * q2;

        float y = 0.0f;
        #pragma unroll
        for (int d = 0; d < 5; ++d) {
            const int n = n0 + d;
            const bool valid = ((unsigned)n < (unsigned)N_);
            const float wd = valid ? w[d] : 0.0f;
            y += wd * ewf[valid ? n : 0];
        }
        local += __logf(fmaf(y, 1.0f / 24.0f, 1e-7f));
    }

    // wave-64 butterfly, then LDS across the block's 16 waves.
    #pragma unroll
    for (int off = 32; off > 0; off >>= 1)
        local += __shfl_down(local, off, 64);

    __shared__ float wpart[THREADS / 64];
    if ((tid & 63) == 0) wpart[tid >> 6] = local;
    __syncthreads();
    if (tid == 0) {
        float s = 0.0f;
        #pragma unroll
        for (int i = 0; i < THREADS / 64; ++i) s += wpart[i];
        partials[blockIdx.x] = s;   // plain store; no atomics, no memset needed
    }
}

__global__ __launch_bounds__(256) void reduce_partials(
    const float* __restrict__ partials, float* __restrict__ out)
{
    const int tid = threadIdx.x;
    float v = partials[tid];        // 256 partials, 256 threads
    #pragma unroll
    for (int off = 32; off > 0; off >>= 1)
        v += __shfl_down(v, off, 64);
    __shared__ float wpart[4];
    if ((tid & 63) == 0) wpart[tid >> 6] = v;
    __syncthreads();
    if (tid == 0) out[0] = wpart[0] + wpart[1] + wpart[2] + wpart[3];
}

extern "C" void kernel_launch(void* const* d_in, const int* in_sizes, int n_in,
                              void* d_out, int out_size, void* d_ws, size_t ws_size,
                              hipStream_t stream) {
    const float* x      = (const float*)d_in[0];
    const float* weight = (const float*)d_in[1];
    float* out      = (float*)d_out;
    float* partials = (float*)d_ws;   // 256 floats of scratch

    spline_partial<<<BLOCKS, THREADS, 0, stream>>>(x, weight, partials);
    reduce_partials<<<1, 256, 0, stream>>>(partials, out);
}